// Round 3
// baseline (125.383 us; speedup 1.0000x reference)
//
#include <hip/hip_runtime.h>

// GLRFast forward: out = patchs - sum_e edge_weights[e] * neighbor_e(patchs)
// Fixed problem: B=4, G=8, C=32, H=128, W=128 (fp32).
// DELTAS order: e0=(-1,0) up, e1=(0,-1) left, e2=(0,+1) right, e3=(+1,0) down.
// Replicate padding == clamped indices.
//
// R8: remove ALL intra-block synchronization. R6/R7 showed stream
// reordering around the barrier is worth ~1us each -> the kernel is
// BW-bound but stuck at ~4.8 TB/s (vs fill's 6.6). Theory: the 32KB LDS
// slab + barrier (a) caps occupancy at 2 blocks/CU, (b) forces the 8
// waves of a block into lockstep so stores bunch and the read queue
// drains in synchronized cohorts device-wide.
// Fix: no LDS, no barrier. Each thread loads its own 4 ew vectors per
// row (the two half-waves of a wave read the SAME 512B segment -> L1
// broadcast; HBM bytes unchanged), 2-deep register ping-pong so ew loads
// stay ahead of use. 256-thread blocks (8 channels), grid 1024 =
// 32bg x 8strip x 4cgroup, 4 blocks/CU = 16 waves/CU, waves free-run ->
// reads and stores of different waves mix naturally.
// __launch_bounds__(256,4): VGPR cap 128 (reg[18]=72 + ewp 32 + addr).

#define GLR_HW 16384   // 128*128 floats per plane

typedef float fvec4 __attribute__((ext_vector_type(4)));

__global__ __launch_bounds__(256, 4) void glr_fwd_kernel(
    const float* __restrict__ patchs,   // [B*G*C, H, W] = 1024 planes
    const float* __restrict__ ew,       // [B*G, 4, H, W]
    float* __restrict__ out)
{
    const int t  = threadIdx.x;
    const int w4 = t & 31;          // vec4 index in row
    const int ch = t >> 5;          // 0..7 channel within cgroup

    // XCD-aware decode: xcd = b&7 (round-robin dispatch heuristic).
    // Per XCD: 4 bgs {xcd,xcd+8,xcd+16,xcd+24}, all (strip,cgroup) pairs
    // consecutive -> ew-slab + halo sharers co-resident on one XCD's L2.
    const int b     = blockIdx.x;              // 0..1023
    const int q     = b >> 3;                  // 0..127 within XCD
    const int bg    = (b & 7) + ((q >> 5) << 3);   // 0..31
    const int rr    = q & 31;
    const int strip = rr >> 2;                 // rows [16s, 16s+16)
    const int cg    = rr & 3;                  // 8-channel group

    const int r0 = strip << 4;
    const int w  = w4 << 2;

    const int plane = (bg << 5) + (cg << 3) + ch;
    const float* __restrict__ P = patchs + (size_t)plane * GLR_HW + w;
    float*       __restrict__ O = out    + (size_t)plane * GLR_HW + w;
    const float* __restrict__ EW = ew + (size_t)bg * 4 * GLR_HW + w;

    // ---- ew ping-pong: rows 0 and 1 issued first (oldest in queue) ----
    float4 ewp[2][4];
    #pragma unroll
    for (int k = 0; k < 4; ++k)
        ewp[0][k] = *(const float4*)(EW + k * GLR_HW + ((r0 + 0) << 7));
    #pragma unroll
    for (int k = 0; k < 4; ++k)
        ewp[1][k] = *(const float4*)(EW + k * GLR_HW + ((r0 + 1) << 7));

    // ---- burst-issue the whole 18-row patch column (independent loads) ----
    float4 reg[18];
    #pragma unroll
    for (int i = 0; i < 18; ++i) {
        int r = r0 + i - 1;
        r = (r < 0) ? 0 : (r > 127 ? 127 : r);
        reg[i] = *(const float4*)(P + (r << 7));
    }

    const bool atL = (w4 == 0);
    const bool atR = (w4 == 31);

    // ---- compute 16 rows; no barrier anywhere, waves free-run ----
    #pragma unroll
    for (int i = 0; i < 16; ++i) {
        const float4 up  = reg[i];
        const float4 cur = reg[i + 1];
        const float4 dn  = reg[i + 2];

        const float4 e0 = ewp[i & 1][0];
        const float4 e1 = ewp[i & 1][1];
        const float4 e2 = ewp[i & 1][2];
        const float4 e3 = ewp[i & 1][3];

        // horizontal neighbors via lane shuffle; channel boundary at the
        // half-wave seam (lanes 31/32) is fixed by the edge clamps.
        float lf = __shfl_up(cur.w, 1);
        float rg = __shfl_down(cur.x, 1);
        if (atL) lf = cur.x;
        if (atR) rg = cur.w;

        fvec4 o;
        o.x = cur.x - (up.x * e0.x + lf    * e1.x + cur.y * e2.x + dn.x * e3.x);
        o.y = cur.y - (up.y * e0.y + cur.x * e1.y + cur.z * e2.y + dn.y * e3.y);
        o.z = cur.z - (up.z * e0.z + cur.y * e1.z + cur.w * e2.z + dn.z * e3.z);
        o.w = cur.w - (up.w * e0.w + cur.z * e1.w + rg    * e2.w + dn.w * e3.w);

        *(fvec4*)(O + ((r0 + i) << 7)) = o;   // normal store (no nt)

        // prefetch ew for row i+2 into the slot just consumed
        // (indices are compile-time constants under full unroll)
        if (i < 14) {
            #pragma unroll
            for (int k = 0; k < 4; ++k)
                ewp[i & 1][k] =
                    *(const float4*)(EW + k * GLR_HW + ((r0 + i + 2) << 7));
        }
    }
}

extern "C" void kernel_launch(void* const* d_in, const int* in_sizes, int n_in,
                              void* d_out, int out_size, void* d_ws, size_t ws_size,
                              hipStream_t stream) {
    const float* patchs = (const float*)d_in[0];  // [4,8,32,128,128]
    const float* ew     = (const float*)d_in[1];  // [4,8,4,128,128]
    // d_in[2] = node_degree, unused in forward
    float* out = (float*)d_out;

    glr_fwd_kernel<<<1024, 256, 0, stream>>>(patchs, ew, out);
}

// Round 4
// 120.101 us; speedup vs baseline: 1.0440x; 1.0440x over previous
//
#include <hip/hip_runtime.h>

// GLRFast forward: out = patchs - sum_e edge_weights[e] * neighbor_e(patchs)
// Fixed problem: B=4, G=8, C=32, H=128, W=128 (fp32).
// DELTAS order: e0=(-1,0) up, e1=(0,-1) left, e2=(0,+1) right, e3=(+1,0) down.
// Replicate padding == clamped indices.
//
// R9: attack DEVICE-WIDE cohort phasing. R6-R8 showed within-block
// scheduling is worth ~1us; the real structure: grid 512 at 2 blocks/CU
// means all blocks are resident from t=0 and none retires -> the whole
// device does its read bursts together, then stores together; read and
// write streams never mix at the HBM controller (kernel ~33us vs 22.7us
// floor; copy ubench proves mixed streams hit 6.3 TB/s).
// Fix: small work quanta + block TURNOVER. 4-row strips, grid 4096 =
// 32bg x 32strip x 4cg, 256-thread blocks, 8KB LDS ew slab,
// __launch_bounds__(256,6) -> ~6 blocks/CU resident, ~2.7 generations:
// retiring blocks' stores overlap fresh blocks' reads continuously.
// Halo over-read (2 of 6 rows) is L2/L3-served; HBM bytes unchanged.
// Keep: XCD decode (strip-neighbors + cg-siblings co-XCD), LDS ew
// staging (R8 showed per-thread ew regresses), normal stores.

#define GLR_HW 16384   // 128*128 floats per plane

typedef float fvec4 __attribute__((ext_vector_type(4)));

__global__ __launch_bounds__(256, 6) void glr_fwd_kernel(
    const float* __restrict__ patchs,   // [B*G*C, H, W] = 1024 planes
    const float* __restrict__ ew,       // [B*G, 4, H, W]
    float* __restrict__ out)
{
    __shared__ float4 sw[512];   // [e:4][row i:4][w4:32] = 8 KB

    const int t  = threadIdx.x;
    const int w4 = t & 31;          // vec4 index in row
    const int ch = t >> 5;          // 0..7 channel within cgroup

    // XCD-aware decode: xcd = b&7 (round-robin dispatch heuristic).
    // Within an XCD enumerate cg fastest, then strip, then bg-quad ->
    // ew-sharers (4 cg) and halo-sharers (adjacent strips) co-XCD.
    const int b     = blockIdx.x;               // 0..4095
    const int q     = b >> 3;                   // 0..511 within XCD
    const int bg    = (b & 7) + ((q >> 7) << 3);   // 0..31
    const int rr    = q & 127;
    const int strip = rr >> 2;                  // rows [4s, 4s+4)
    const int cg    = rr & 3;                   // 8-channel group

    const int r0 = strip << 2;
    const int w  = w4 << 2;

    const int plane = (bg << 5) + (cg << 3) + ch;
    const float* __restrict__ P = patchs + (size_t)plane * GLR_HW + w;
    float*       __restrict__ O = out    + (size_t)plane * GLR_HW + w;

    // ---- ew slab loads first (oldest in vmcnt queue): 2 per thread ----
    {
        const float* __restrict__ EW = ew + (size_t)bg * 4 * GLR_HW;
        #pragma unroll
        for (int k = 0; k < 2; ++k) {
            const int j  = t + (k << 8);     // 0..511
            const int e  = j >> 7;
            const int i  = (j >> 5) & 3;
            const int wq = j & 31;
            sw[j] = *(const float4*)(EW + e * GLR_HW + ((r0 + i) << 7) + (wq << 2));
        }
    }

    // ---- burst-issue the 6-row patch column (4 + 2 halo) ----
    float4 reg[6];
    #pragma unroll
    for (int i = 0; i < 6; ++i) {
        int r = r0 + i - 1;
        r = (r < 0) ? 0 : (r > 127 ? 127 : r);
        reg[i] = *(const float4*)(P + (r << 7));
    }

    __syncthreads();   // drains 8 concurrent loads (~one HBM latency)

    const bool atL = (w4 == 0);
    const bool atR = (w4 == 31);

    // ---- compute 4 rows from registers ----
    #pragma unroll
    for (int i = 0; i < 4; ++i) {
        const float4 up  = reg[i];
        const float4 cur = reg[i + 1];
        const float4 dn  = reg[i + 2];

        const int si = (i << 5) + w4;
        const float4 e0 = sw[si];
        const float4 e1 = sw[128 + si];
        const float4 e2 = sw[256 + si];
        const float4 e3 = sw[384 + si];

        // horizontal neighbors via lane shuffle; channel boundary at the
        // half-wave seam (lanes 31/32) is fixed by the edge clamps.
        float lf = __shfl_up(cur.w, 1);
        float rg = __shfl_down(cur.x, 1);
        if (atL) lf = cur.x;
        if (atR) rg = cur.w;

        fvec4 o;
        o.x = cur.x - (up.x * e0.x + lf    * e1.x + cur.y * e2.x + dn.x * e3.x);
        o.y = cur.y - (up.y * e0.y + cur.x * e1.y + cur.z * e2.y + dn.y * e3.y);
        o.z = cur.z - (up.z * e0.z + cur.y * e1.z + cur.w * e2.z + dn.z * e3.z);
        o.w = cur.w - (up.w * e0.w + cur.z * e1.w + rg    * e2.w + dn.w * e3.w);

        *(fvec4*)(O + ((r0 + i) << 7)) = o;   // normal store (no nt)
    }
}

extern "C" void kernel_launch(void* const* d_in, const int* in_sizes, int n_in,
                              void* d_out, int out_size, void* d_ws, size_t ws_size,
                              hipStream_t stream) {
    const float* patchs = (const float*)d_in[0];  // [4,8,32,128,128]
    const float* ew     = (const float*)d_in[1];  // [4,8,4,128,128]
    // d_in[2] = node_degree, unused in forward
    float* out = (float*)d_out;

    glr_fwd_kernel<<<4096, 256, 0, stream>>>(patchs, ew, out);
}